// Round 4
// baseline (2005.038 us; speedup 1.0000x reference)
//
#include <hip/hip_runtime.h>

typedef unsigned short u16;
typedef __attribute__((ext_vector_type(8))) short short8;
typedef __attribute__((ext_vector_type(4))) float f32x4;

#define N_NODES 40000
#define N_EDGES 640000

// ---------- bf16 helpers (RNE) ----------
__device__ __forceinline__ u16 f2bf(float f) {
  unsigned int u = __builtin_bit_cast(unsigned int, f);
  u += 0x7FFFu + ((u >> 16) & 1u);
  return (u16)(u >> 16);
}

// ---------- prep: W1/W2 f32 -> bf16, permuted into MFMA B-fragment order ----
// B frag for (ntile,ks): lane l holds B[k=ks*32+(l>>4)*8+j][n=ntile*16+(l&15)]
__global__ void prep_weights(const float* __restrict__ W1,
                             const float* __restrict__ W2,
                             u16* __restrict__ w1t, u16* __restrict__ w2t) {
  int gid = blockIdx.x * 256 + threadIdx.x;
  if (gid < 3 * 16 * 8 * 64) {            // W1: 3 layers x 16 ntiles x 8 ks x 64 lanes
    int l = gid >> 13;
    int rem = gid & 8191;
    int ntg = rem >> 9;
    int ks = (rem >> 6) & 7;
    int lane = rem & 63;
    int n = ntg * 16 + (lane & 15);
    int k0 = ks * 32 + (lane >> 4) * 8;
    const float* s = W1 + l * 65536 + n * 256 + k0;
    u16* d = w1t + (size_t)gid * 8;
#pragma unroll
    for (int j = 0; j < 8; ++j) d[j] = f2bf(s[j]);
  } else if (gid < 3 * 16 * 8 * 64 + 3 * 8 * 8 * 64) {  // W2: 8 ntiles
    int g = gid - 3 * 16 * 8 * 64;
    int l = g >> 12;
    int rem = g & 4095;
    int ntg = rem >> 9;
    int ks = (rem >> 6) & 7;
    int lane = rem & 63;
    int n = ntg * 16 + (lane & 15);
    int k0 = ks * 32 + (lane >> 4) * 8;
    const float* s = W2 + l * 32768 + n * 256 + k0;
    u16* d = w2t + (size_t)g * 8;
#pragma unroll
    for (int j = 0; j < 8; ++j) d[j] = f2bf(s[j]);
  }
}

// ---------- f32 -> bf16 (optional relu), vectorized x8 ----------
__global__ void cvt_vec(const float* __restrict__ in, u16* __restrict__ out,
                        int n8, int dorelu) {
  int i = blockIdx.x * 256 + threadIdx.x;
  if (i >= n8) return;
  const float4* p = reinterpret_cast<const float4*>(in) + (size_t)i * 2;
  float4 a = p[0], b = p[1];
  if (dorelu) {
    a.x = fmaxf(a.x, 0.f); a.y = fmaxf(a.y, 0.f);
    a.z = fmaxf(a.z, 0.f); a.w = fmaxf(a.w, 0.f);
    b.x = fmaxf(b.x, 0.f); b.y = fmaxf(b.y, 0.f);
    b.z = fmaxf(b.z, 0.f); b.w = fmaxf(b.w, 0.f);
  }
  short8 v;
  v[0] = (short)f2bf(a.x); v[1] = (short)f2bf(a.y);
  v[2] = (short)f2bf(a.z); v[3] = (short)f2bf(a.w);
  v[4] = (short)f2bf(b.x); v[5] = (short)f2bf(b.y);
  v[6] = (short)f2bf(b.z); v[7] = (short)f2bf(b.w);
  *reinterpret_cast<short8*>(out + (size_t)i * 8) = v;
}

// ---------- counting sort of edges by dst ----------
__global__ void hist_dst(const int* __restrict__ dst, int* __restrict__ cnt) {
  int e = blockIdx.x * 256 + threadIdx.x;
  if (e < N_EDGES) atomicAdd(&cnt[dst[e]], 1);
}

__global__ void scan_hist(const int* __restrict__ cnt, int* __restrict__ cursor) {
  __shared__ int ls[1024];
  const int tid = threadIdx.x;  // 1024 threads, 40 nodes each
  const int b = tid * 40;
  const int lim = (b < N_NODES) ? ((N_NODES - b < 40) ? (N_NODES - b) : 40) : 0;
  int s = 0;
  for (int j = 0; j < lim; ++j) s += cnt[b + j];
  ls[tid] = s;
  __syncthreads();
  for (int off = 1; off < 1024; off <<= 1) {
    int v = (tid >= off) ? ls[tid - off] : 0;
    __syncthreads();
    ls[tid] += v;
    __syncthreads();
  }
  int run = (tid == 0) ? 0 : ls[tid - 1];
  for (int j = 0; j < lim; ++j) {
    cursor[b + j] = run;
    run += cnt[b + j];
  }
}

__global__ void rank_edges(const int* __restrict__ src, const int* __restrict__ dst,
                           int* __restrict__ cursor, int* __restrict__ srcS,
                           int* __restrict__ dstS, int* __restrict__ eperm) {
  int e = blockIdx.x * 256 + threadIdx.x;
  if (e >= N_EDGES) return;
  int d = dst[e];
  int r = atomicAdd(&cursor[d], 1);
  eperm[r] = e;
  srcS[r] = src[e];
  dstS[r] = d;
}

// ---------- k1: x[slot][256] = concat(h[srcS],e[eperm]) @ W1^T + col stats --
// Edges in dst-sorted slot order. A-fragments direct from global.
// Epilogue: C-frags -> LDS transpose -> coalesced short8 stores (R4 change).
template <bool RELU_E>
__global__ __launch_bounds__(256) void gin_g1(
    const u16* __restrict__ hbf, const float* __restrict__ ef32,
    const int* __restrict__ srcS, const int* __restrict__ eperm,
    const u16* __restrict__ w1t, u16* __restrict__ xout,
    float* __restrict__ stats) {
  __shared__ u16 sT[64][264];  // +8 pad; row stride 528B (16B-aligned)
  const int tid = threadIdx.x;
  const long e0 = (long)blockIdx.x * 64;
  const int wid = tid >> 6, lane = tid & 63;
  const int lrow = lane & 15, lk = lane >> 4;
  int s4[4], ep[4];
#pragma unroll
  for (int mt = 0; mt < 4; ++mt) {
    s4[mt] = srcS[e0 + mt * 16 + lrow];
    ep[mt] = eperm[e0 + mt * 16 + lrow];
  }
  f32x4 acc[4][4] = {};
  const u16* wbase = w1t + (size_t)wid * 16384;
  for (int ks = 0; ks < 8; ++ks) {
    short8 af[4];
#pragma unroll
    for (int mt = 0; mt < 4; ++mt) {
      if (ks < 4) {
        af[mt] = *(const short8*)(hbf + (size_t)s4[mt] * 128 + ks * 32 + lk * 8);
      } else {
        const float4* p = reinterpret_cast<const float4*>(
            ef32 + (size_t)ep[mt] * 128 + (ks - 4) * 32 + lk * 8);
        float4 f0 = p[0], f1 = p[1];
        if (RELU_E) {
          f0.x = fmaxf(f0.x, 0.f); f0.y = fmaxf(f0.y, 0.f);
          f0.z = fmaxf(f0.z, 0.f); f0.w = fmaxf(f0.w, 0.f);
          f1.x = fmaxf(f1.x, 0.f); f1.y = fmaxf(f1.y, 0.f);
          f1.z = fmaxf(f1.z, 0.f); f1.w = fmaxf(f1.w, 0.f);
        }
        short8 v;
        v[0] = (short)f2bf(f0.x); v[1] = (short)f2bf(f0.y);
        v[2] = (short)f2bf(f0.z); v[3] = (short)f2bf(f0.w);
        v[4] = (short)f2bf(f1.x); v[5] = (short)f2bf(f1.y);
        v[6] = (short)f2bf(f1.z); v[7] = (short)f2bf(f1.w);
        af[mt] = v;
      }
    }
#pragma unroll
    for (int nt = 0; nt < 4; ++nt) {
      short8 bf = *(const short8*)(wbase + ((nt * 8 + ks) * 64 + lane) * 8);
#pragma unroll
      for (int mt = 0; mt < 4; ++mt)
        acc[mt][nt] =
            __builtin_amdgcn_mfma_f32_16x16x32_bf16(af[mt], bf, acc[mt][nt], 0, 0, 0);
    }
  }
  // ---- stats from registers (as before), C-frags -> LDS (bf16)
  float* statp = stats + (blockIdx.x & 63) * 512;
#pragma unroll
  for (int nt = 0; nt < 4; ++nt) {
    const int col = wid * 64 + nt * 16 + lrow;
    float sm = 0.f, sq = 0.f;
#pragma unroll
    for (int mt = 0; mt < 4; ++mt) {
#pragma unroll
      for (int i = 0; i < 4; ++i) {
        float v = acc[mt][nt][i];
        sT[mt * 16 + lk * 4 + i][col] = f2bf(v);
        sm += v; sq += v * v;
      }
    }
    sm += __shfl_xor(sm, 16); sq += __shfl_xor(sq, 16);
    sm += __shfl_xor(sm, 32); sq += __shfl_xor(sq, 32);
    if (lk == 0) {
      atomicAdd(statp + col, sm);
      atomicAdd(statp + 256 + col, sq);
    }
  }
  __syncthreads();
  // ---- coalesced x store: 8 x short8 (16B) per thread, wave = 1KB dense
#pragma unroll
  for (int it = 0; it < 8; ++it) {
    const int idx = it * 256 + tid;      // 2048 short8 chunks in the tile
    const int r = idx >> 5, c8 = idx & 31;
    short8 v = *(const short8*)&sT[r][c8 * 8];
    *(short8*)(xout + (size_t)(e0 + r) * 256 + c8 * 8) = v;
  }
}

// ---------- BN finalize: a = gamma*rsqrt(var+eps), b = beta - mu*a ----------
__global__ void gin_bnstats(const float* __restrict__ stats,
                            const float* __restrict__ gamma,
                            const float* __restrict__ beta,
                            float* __restrict__ ab) {
  int c = threadIdx.x;  // 256 threads
  float sm = 0.f, sq = 0.f;
  for (int i = 0; i < 64; ++i) {
    sm += stats[i * 512 + c];
    sq += stats[i * 512 + 256 + c];
  }
  const float inv = 1.0f / (float)N_EDGES;
  float mu = sm * inv;
  float var = fmaxf(sq * inv - mu * mu, 0.f);
  float a = gamma[c] * rsqrtf(var + 1e-5f);
  ab[c] = a;
  ab[256 + c] = beta[c] - mu * a;
}

// ---------- k2: m = relu(x*a+b) @ W2^T ; run-compressed scatter to dstS -----
__global__ __launch_bounds__(256) void gin_g2(
    const u16* __restrict__ xin, const u16* __restrict__ w2t,
    const float* __restrict__ ab, const float* __restrict__ b2,
    const int* __restrict__ dstS, float* __restrict__ hnext) {
  __shared__ u16 sX[64][264];
  const int tid = threadIdx.x;
  const long e0 = (long)blockIdx.x * 64;

  // ---- stage normalized+relu'd x tile (bf16), x read fully sequential
  {
    const int c = tid & 31;
    const int kb = c * 8;
    float a_[8], s_[8];
#pragma unroll
    for (int j = 0; j < 8; ++j) { a_[j] = ab[kb + j]; s_[j] = ab[256 + kb + j]; }
    for (int it = 0; it < 8; ++it) {
      const int r = it * 8 + (tid >> 5);
      short8 u = *(const short8*)(xin + (size_t)(e0 + r) * 256 + kb);
      short8 v;
#pragma unroll
      for (int j = 0; j < 8; ++j) {
        unsigned int w = ((unsigned int)(u16)u[j]) << 16;
        float f = __builtin_bit_cast(float, w);
        f = fmaxf(f * a_[j] + s_[j], 0.f);
        v[j] = (short)f2bf(f);
      }
      *(short8*)&sX[r][kb] = v;
    }
  }
  __syncthreads();

  const int wid = tid >> 6, lane = tid & 63;
  const int lrow = lane & 15, lk = lane >> 4;
  f32x4 acc2[4][2] = {};
  const u16* wb2 = w2t + (size_t)wid * 8192;
  for (int ks = 0; ks < 8; ++ks) {
    short8 af[4];
#pragma unroll
    for (int mt = 0; mt < 4; ++mt)
      af[mt] = *(const short8*)&sX[mt * 16 + lrow][ks * 32 + lk * 8];
#pragma unroll
    for (int nt = 0; nt < 2; ++nt) {
      short8 bf = *(const short8*)(wb2 + ((nt * 8 + ks) * 64 + lane) * 8);
#pragma unroll
      for (int mt = 0; mt < 4; ++mt)
        acc2[mt][nt] =
            __builtin_amdgcn_mfma_f32_16x16x32_bf16(af[mt], bf, acc2[mt][nt], 0, 0, 0);
    }
  }

  // ---- epilogue: dst-sorted run compression, then atomicAdd per run
  int nd[4][4];
#pragma unroll
  for (int mt = 0; mt < 4; ++mt)
#pragma unroll
    for (int i = 0; i < 4; ++i) nd[mt][i] = dstS[e0 + mt * 16 + lk * 4 + i];
  float bb[2];
#pragma unroll
  for (int nt = 0; nt < 2; ++nt) bb[nt] = b2[wid * 32 + nt * 16 + lrow];
#pragma unroll
  for (int nt = 0; nt < 2; ++nt) {
    const int col = wid * 32 + nt * 16 + lrow;
    float carry = 0.f;
    int cur = nd[0][0];
#pragma unroll
    for (int mt = 0; mt < 4; ++mt) {
#pragma unroll
      for (int i = 0; i < 4; ++i) {
        int n_ = nd[mt][i];
        if (n_ != cur) {
          atomicAdd(hnext + (size_t)cur * 128 + col, carry);
          carry = 0.f;
          cur = n_;
        }
        carry += acc2[mt][nt][i] + bb[nt];
      }
    }
    atomicAdd(hnext + (size_t)cur * 128 + col, carry);
  }
}

// ---------- launch ----------
extern "C" void kernel_launch(void* const* d_in, const int* in_sizes, int n_in,
                              void* d_out, int out_size, void* d_ws, size_t ws_size,
                              hipStream_t stream) {
  const float* h     = (const float*)d_in[0];
  const float* e     = (const float*)d_in[1];
  const float* W1    = (const float*)d_in[2];
  // d_in[3] = b1: cancels exactly in BatchNorm -> unused
  const float* gamma = (const float*)d_in[4];
  const float* beta  = (const float*)d_in[5];
  const float* W2    = (const float*)d_in[6];
  const float* b2    = (const float*)d_in[7];
  const int* src     = (const int*)d_in[8];
  const int* dst     = (const int*)d_in[9];
  float* out = (float*)d_out;

  char* ws = (char*)d_ws;
  u16*   xbuf   = (u16*)(ws);                     // 327,680,000
  u16*   hbf    = (u16*)(ws + 327680000);         // 10,240,000
  float* h1     = (float*)(ws + 337920000);       // 20,480,000
  u16*   w1t    = (u16*)(ws + 358400000);         // 393,216
  u16*   w2t    = (u16*)(ws + 358793216);         // 196,608
  float* stats  = (float*)(ws + 358989824);       // 131,072
  float* ab     = (float*)(ws + 359120896);       // 2,048
  int*   cnt    = (int*)(ws + 359122944);         // 160,000
  int*   cursor = (int*)(ws + 359282944);         // 160,000
  int*   srcS   = (int*)(ws + 359442944);         // 2,560,000
  int*   dstS   = (int*)(ws + 362002944);         // 2,560,000
  int*   eperm  = (int*)(ws + 364562944);         // 2,560,000

  prep_weights<<<144, 256, 0, stream>>>(W1, W2, w1t, w2t);
  cvt_vec<<<2500, 256, 0, stream>>>(h, hbf, 640000, 0);  // h -> bf16 (no relu)

  // counting sort of edges by dst (dst static across layers)
  hipMemsetAsync(cnt, 0, 160000, stream);
  hist_dst<<<2500, 256, 0, stream>>>(dst, cnt);
  scan_hist<<<1, 1024, 0, stream>>>(cnt, cursor);
  rank_edges<<<2500, 256, 0, stream>>>(src, dst, cursor, srcS, dstS, eperm);

  const int nblk = N_EDGES / 64;  // 10000
  for (int l = 0; l < 3; ++l) {
    hipMemsetAsync(stats, 0, 64 * 512 * 4, stream);
    if (l == 0)
      gin_g1<false><<<nblk, 256, 0, stream>>>(hbf, e, srcS, eperm, w1t, xbuf, stats);
    else
      gin_g1<true><<<nblk, 256, 0, stream>>>(hbf, e, srcS, eperm,
                                             w1t + (size_t)l * 65536, xbuf, stats);
    gin_bnstats<<<1, 256, 0, stream>>>(stats, gamma + l * 256, beta + l * 256, ab);
    float* hnext = (l < 2) ? h1 : out;
    hipMemsetAsync(hnext, 0, (size_t)N_NODES * 128 * 4, stream);
    gin_g2<<<nblk, 256, 0, stream>>>(xbuf, w2t + (size_t)l * 32768, ab,
                                     b2 + l * 128, dstS, hnext);
    if (l < 2) cvt_vec<<<2500, 256, 0, stream>>>(h1, hbf, 640000, 1);
  }
}

// Round 5
// 1761.562 us; speedup vs baseline: 1.1382x; 1.1382x over previous
//
#include <hip/hip_runtime.h>

typedef unsigned short u16;
typedef __attribute__((ext_vector_type(8))) short short8;
typedef __attribute__((ext_vector_type(4))) float f32x4;

#define N_NODES 40000
#define N_EDGES 640000

// ---------- bf16 helpers (RNE) ----------
__device__ __forceinline__ u16 f2bf(float f) {
  unsigned int u = __builtin_bit_cast(unsigned int, f);
  u += 0x7FFFu + ((u >> 16) & 1u);
  return (u16)(u >> 16);
}

// ---------- prep: W1/W2 f32 -> bf16, permuted into MFMA B-fragment order ----
// B frag for (ntile,ks): lane l holds B[k=ks*32+(l>>4)*8+j][n=ntile*16+(l&15)]
__global__ void prep_weights(const float* __restrict__ W1,
                             const float* __restrict__ W2,
                             u16* __restrict__ w1t, u16* __restrict__ w2t) {
  int gid = blockIdx.x * 256 + threadIdx.x;
  if (gid < 3 * 16 * 8 * 64) {            // W1: 3 layers x 16 ntiles x 8 ks x 64 lanes
    int l = gid >> 13;
    int rem = gid & 8191;
    int ntg = rem >> 9;
    int ks = (rem >> 6) & 7;
    int lane = rem & 63;
    int n = ntg * 16 + (lane & 15);
    int k0 = ks * 32 + (lane >> 4) * 8;
    const float* s = W1 + l * 65536 + n * 256 + k0;
    u16* d = w1t + (size_t)gid * 8;
#pragma unroll
    for (int j = 0; j < 8; ++j) d[j] = f2bf(s[j]);
  } else if (gid < 3 * 16 * 8 * 64 + 3 * 8 * 8 * 64) {  // W2: 8 ntiles
    int g = gid - 3 * 16 * 8 * 64;
    int l = g >> 12;
    int rem = g & 4095;
    int ntg = rem >> 9;
    int ks = (rem >> 6) & 7;
    int lane = rem & 63;
    int n = ntg * 16 + (lane & 15);
    int k0 = ks * 32 + (lane >> 4) * 8;
    const float* s = W2 + l * 32768 + n * 256 + k0;
    u16* d = w2t + (size_t)g * 8;
#pragma unroll
    for (int j = 0; j < 8; ++j) d[j] = f2bf(s[j]);
  }
}

// ---------- f32 -> bf16 (optional relu), vectorized x8 ----------
__global__ void cvt_vec(const float* __restrict__ in, u16* __restrict__ out,
                        int n8, int dorelu) {
  int i = blockIdx.x * 256 + threadIdx.x;
  if (i >= n8) return;
  const float4* p = reinterpret_cast<const float4*>(in) + (size_t)i * 2;
  float4 a = p[0], b = p[1];
  if (dorelu) {
    a.x = fmaxf(a.x, 0.f); a.y = fmaxf(a.y, 0.f);
    a.z = fmaxf(a.z, 0.f); a.w = fmaxf(a.w, 0.f);
    b.x = fmaxf(b.x, 0.f); b.y = fmaxf(b.y, 0.f);
    b.z = fmaxf(b.z, 0.f); b.w = fmaxf(b.w, 0.f);
  }
  short8 v;
  v[0] = (short)f2bf(a.x); v[1] = (short)f2bf(a.y);
  v[2] = (short)f2bf(a.z); v[3] = (short)f2bf(a.w);
  v[4] = (short)f2bf(b.x); v[5] = (short)f2bf(b.y);
  v[6] = (short)f2bf(b.z); v[7] = (short)f2bf(b.w);
  *reinterpret_cast<short8*>(out + (size_t)i * 8) = v;
}

// ---------- counting sort of edges by dst ----------
__global__ void hist_dst(const int* __restrict__ dst, int* __restrict__ cnt) {
  int e = blockIdx.x * 256 + threadIdx.x;
  if (e < N_EDGES) atomicAdd(&cnt[dst[e]], 1);
}

__global__ void scan_hist(const int* __restrict__ cnt, int* __restrict__ cursor) {
  __shared__ int ls[1024];
  const int tid = threadIdx.x;  // 1024 threads, 40 nodes each
  const int b = tid * 40;
  const int lim = (b < N_NODES) ? ((N_NODES - b < 40) ? (N_NODES - b) : 40) : 0;
  int s = 0;
  for (int j = 0; j < lim; ++j) s += cnt[b + j];
  ls[tid] = s;
  __syncthreads();
  for (int off = 1; off < 1024; off <<= 1) {
    int v = (tid >= off) ? ls[tid - off] : 0;
    __syncthreads();
    ls[tid] += v;
    __syncthreads();
  }
  int run = (tid == 0) ? 0 : ls[tid - 1];
  for (int j = 0; j < lim; ++j) {
    cursor[b + j] = run;
    run += cnt[b + j];
  }
}

__global__ void rank_edges(const int* __restrict__ src, const int* __restrict__ dst,
                           int* __restrict__ cursor, int* __restrict__ srcS,
                           int* __restrict__ dstS, int* __restrict__ rank) {
  int e = blockIdx.x * 256 + threadIdx.x;
  if (e >= N_EDGES) return;
  int d = dst[e];
  int r = atomicAdd(&cursor[d], 1);
  rank[e] = r;
  srcS[r] = src[e];
  dstS[r] = d;
}

// ---------- permute e into sorted slot order, f32 -> bf16 (raw, no relu) ----
// Read fully sequential; write 256B-contiguous rows scattered by rank.
__global__ void permute_e(const float* __restrict__ e, const int* __restrict__ rank,
                          u16* __restrict__ ebfS) {
  int t = blockIdx.x * 256 + threadIdx.x;
  int row = t >> 2;
  int part = t & 3;  // 32-float chunk of the row
  if (row >= N_EDGES) return;
  const float4* p = reinterpret_cast<const float4*>(e + (size_t)row * 128 + part * 32);
  u16* dp = ebfS + (size_t)rank[row] * 128 + part * 32;
#pragma unroll
  for (int j = 0; j < 4; ++j) {
    float4 a = p[j * 2], b = p[j * 2 + 1];
    short8 v;
    v[0] = (short)f2bf(a.x); v[1] = (short)f2bf(a.y);
    v[2] = (short)f2bf(a.z); v[3] = (short)f2bf(a.w);
    v[4] = (short)f2bf(b.x); v[5] = (short)f2bf(b.y);
    v[6] = (short)f2bf(b.z); v[7] = (short)f2bf(b.w);
    *(short8*)(dp + j * 8) = v;
  }
}

// ---------- in-place relu on packed bf16 (sign-mask trick) ----------
__global__ void relu_bf16_inplace(unsigned int* __restrict__ p, int n4) {
  int i = blockIdx.x * 256 + threadIdx.x;
  if (i >= n4) return;
  uint4 v = reinterpret_cast<uint4*>(p)[i];
#pragma unroll
  for (int j = 0; j < 4; ++j) {
    unsigned int u = (&v.x)[j];
    unsigned int t = (u >> 15) & 0x10001u;   // sign bits of both bf16 halves
    (&v.x)[j] = u & ~(t * 0xFFFFu);          // zero negative halves
  }
  reinterpret_cast<uint4*>(p)[i] = v;
}

// ---------- k1: x[row][256] = concat(h[srcIdx],e) @ W1^T + col stats --------
// Rows processed sequentially. EMODE: 0 = f32 e (raw), 1 = f32 e + relu,
// 2 = bf16 e (pre-relu'd externally). Epilogue: LDS -> coalesced short8.
template <int EMODE>
__global__ __launch_bounds__(256) void gin_g1(
    const u16* __restrict__ hbf, const float* __restrict__ ef32,
    const u16* __restrict__ ebf, const int* __restrict__ srcIdx,
    const u16* __restrict__ w1t, u16* __restrict__ xout,
    float* __restrict__ stats) {
  __shared__ u16 sT[64][264];
  const int tid = threadIdx.x;
  const long e0 = (long)blockIdx.x * 64;
  const int wid = tid >> 6, lane = tid & 63;
  const int lrow = lane & 15, lk = lane >> 4;
  int s4[4];
#pragma unroll
  for (int mt = 0; mt < 4; ++mt) s4[mt] = srcIdx[e0 + mt * 16 + lrow];
  f32x4 acc[4][4] = {};
  const u16* wbase = w1t + (size_t)wid * 16384;
  for (int ks = 0; ks < 8; ++ks) {
    short8 af[4];
#pragma unroll
    for (int mt = 0; mt < 4; ++mt) {
      const long row = e0 + mt * 16 + lrow;
      if (ks < 4) {
        af[mt] = *(const short8*)(hbf + (size_t)s4[mt] * 128 + ks * 32 + lk * 8);
      } else if (EMODE == 2) {
        af[mt] = *(const short8*)(ebf + (size_t)row * 128 + (ks - 4) * 32 + lk * 8);
      } else {
        const float4* p = reinterpret_cast<const float4*>(
            ef32 + (size_t)row * 128 + (ks - 4) * 32 + lk * 8);
        float4 f0 = p[0], f1 = p[1];
        if (EMODE == 1) {
          f0.x = fmaxf(f0.x, 0.f); f0.y = fmaxf(f0.y, 0.f);
          f0.z = fmaxf(f0.z, 0.f); f0.w = fmaxf(f0.w, 0.f);
          f1.x = fmaxf(f1.x, 0.f); f1.y = fmaxf(f1.y, 0.f);
          f1.z = fmaxf(f1.z, 0.f); f1.w = fmaxf(f1.w, 0.f);
        }
        short8 v;
        v[0] = (short)f2bf(f0.x); v[1] = (short)f2bf(f0.y);
        v[2] = (short)f2bf(f0.z); v[3] = (short)f2bf(f0.w);
        v[4] = (short)f2bf(f1.x); v[5] = (short)f2bf(f1.y);
        v[6] = (short)f2bf(f1.z); v[7] = (short)f2bf(f1.w);
        af[mt] = v;
      }
    }
#pragma unroll
    for (int nt = 0; nt < 4; ++nt) {
      short8 bf = *(const short8*)(wbase + ((nt * 8 + ks) * 64 + lane) * 8);
#pragma unroll
      for (int mt = 0; mt < 4; ++mt)
        acc[mt][nt] =
            __builtin_amdgcn_mfma_f32_16x16x32_bf16(af[mt], bf, acc[mt][nt], 0, 0, 0);
    }
  }
  // ---- stats from registers, C-frags -> LDS (bf16)
  float* statp = stats + (blockIdx.x & 63) * 512;
#pragma unroll
  for (int nt = 0; nt < 4; ++nt) {
    const int col = wid * 64 + nt * 16 + lrow;
    float sm = 0.f, sq = 0.f;
#pragma unroll
    for (int mt = 0; mt < 4; ++mt) {
#pragma unroll
      for (int i = 0; i < 4; ++i) {
        float v = acc[mt][nt][i];
        sT[mt * 16 + lk * 4 + i][col] = f2bf(v);
        sm += v; sq += v * v;
      }
    }
    sm += __shfl_xor(sm, 16); sq += __shfl_xor(sq, 16);
    sm += __shfl_xor(sm, 32); sq += __shfl_xor(sq, 32);
    if (lk == 0) {
      atomicAdd(statp + col, sm);
      atomicAdd(statp + 256 + col, sq);
    }
  }
  __syncthreads();
  // ---- coalesced x store: 8 x short8 (16B) per thread
#pragma unroll
  for (int it = 0; it < 8; ++it) {
    const int idx = it * 256 + tid;
    const int r = idx >> 5, c8 = idx & 31;
    short8 v = *(const short8*)&sT[r][c8 * 8];
    *(short8*)(xout + (size_t)(e0 + r) * 256 + c8 * 8) = v;
  }
}

// ---------- BN finalize: a = gamma*rsqrt(var+eps), b = beta - mu*a ----------
__global__ void gin_bnstats(const float* __restrict__ stats,
                            const float* __restrict__ gamma,
                            const float* __restrict__ beta,
                            float* __restrict__ ab) {
  int c = threadIdx.x;  // 256 threads
  float sm = 0.f, sq = 0.f;
  for (int i = 0; i < 64; ++i) {
    sm += stats[i * 512 + c];
    sq += stats[i * 512 + 256 + c];
  }
  const float inv = 1.0f / (float)N_EDGES;
  float mu = sm * inv;
  float var = fmaxf(sq * inv - mu * mu, 0.f);
  float a = gamma[c] * rsqrtf(var + 1e-5f);
  ab[c] = a;
  ab[256 + c] = beta[c] - mu * a;
}

// ---------- k2: m = relu(x*a+b) @ W2^T ; scatter to dstArr ------------------
// SORTED: run-compressed atomics (dst-sorted rows); else plain atomics.
template <bool SORTED>
__global__ __launch_bounds__(256) void gin_g2(
    const u16* __restrict__ xin, const u16* __restrict__ w2t,
    const float* __restrict__ ab, const float* __restrict__ b2,
    const int* __restrict__ dstArr, float* __restrict__ hnext) {
  __shared__ u16 sX[64][264];
  const int tid = threadIdx.x;
  const long e0 = (long)blockIdx.x * 64;

  // ---- stage normalized+relu'd x tile (bf16), x read fully sequential
  {
    const int c = tid & 31;
    const int kb = c * 8;
    float a_[8], s_[8];
#pragma unroll
    for (int j = 0; j < 8; ++j) { a_[j] = ab[kb + j]; s_[j] = ab[256 + kb + j]; }
    for (int it = 0; it < 8; ++it) {
      const int r = it * 8 + (tid >> 5);
      short8 u = *(const short8*)(xin + (size_t)(e0 + r) * 256 + kb);
      short8 v;
#pragma unroll
      for (int j = 0; j < 8; ++j) {
        unsigned int w = ((unsigned int)(u16)u[j]) << 16;
        float f = __builtin_bit_cast(float, w);
        f = fmaxf(f * a_[j] + s_[j], 0.f);
        v[j] = (short)f2bf(f);
      }
      *(short8*)&sX[r][kb] = v;
    }
  }
  __syncthreads();

  const int wid = tid >> 6, lane = tid & 63;
  const int lrow = lane & 15, lk = lane >> 4;
  f32x4 acc2[4][2] = {};
  const u16* wb2 = w2t + (size_t)wid * 8192;
  for (int ks = 0; ks < 8; ++ks) {
    short8 af[4];
#pragma unroll
    for (int mt = 0; mt < 4; ++mt)
      af[mt] = *(const short8*)&sX[mt * 16 + lrow][ks * 32 + lk * 8];
#pragma unroll
    for (int nt = 0; nt < 2; ++nt) {
      short8 bf = *(const short8*)(wb2 + ((nt * 8 + ks) * 64 + lane) * 8);
#pragma unroll
      for (int mt = 0; mt < 4; ++mt)
        acc2[mt][nt] =
            __builtin_amdgcn_mfma_f32_16x16x32_bf16(af[mt], bf, acc2[mt][nt], 0, 0, 0);
    }
  }

  int nd[4][4];
#pragma unroll
  for (int mt = 0; mt < 4; ++mt)
#pragma unroll
    for (int i = 0; i < 4; ++i) nd[mt][i] = dstArr[e0 + mt * 16 + lk * 4 + i];
  float bb[2];
#pragma unroll
  for (int nt = 0; nt < 2; ++nt) bb[nt] = b2[wid * 32 + nt * 16 + lrow];
  if (SORTED) {
#pragma unroll
    for (int nt = 0; nt < 2; ++nt) {
      const int col = wid * 32 + nt * 16 + lrow;
      float carry = 0.f;
      int cur = nd[0][0];
#pragma unroll
      for (int mt = 0; mt < 4; ++mt) {
#pragma unroll
        for (int i = 0; i < 4; ++i) {
          int n_ = nd[mt][i];
          if (n_ != cur) {
            atomicAdd(hnext + (size_t)cur * 128 + col, carry);
            carry = 0.f;
            cur = n_;
          }
          carry += acc2[mt][nt][i] + bb[nt];
        }
      }
      atomicAdd(hnext + (size_t)cur * 128 + col, carry);
    }
  } else {
#pragma unroll
    for (int nt = 0; nt < 2; ++nt) {
      const int col = wid * 32 + nt * 16 + lrow;
#pragma unroll
      for (int mt = 0; mt < 4; ++mt)
#pragma unroll
        for (int i = 0; i < 4; ++i)
          atomicAdd(hnext + (size_t)nd[mt][i] * 128 + col,
                    acc2[mt][nt][i] + bb[nt]);
    }
  }
}

// ---------- launch ----------
extern "C" void kernel_launch(void* const* d_in, const int* in_sizes, int n_in,
                              void* d_out, int out_size, void* d_ws, size_t ws_size,
                              hipStream_t stream) {
  const float* h     = (const float*)d_in[0];
  const float* e     = (const float*)d_in[1];
  const float* W1    = (const float*)d_in[2];
  // d_in[3] = b1: cancels exactly in BatchNorm -> unused
  const float* gamma = (const float*)d_in[4];
  const float* beta  = (const float*)d_in[5];
  const float* W2    = (const float*)d_in[6];
  const float* b2    = (const float*)d_in[7];
  const int* src     = (const int*)d_in[8];
  const int* dst     = (const int*)d_in[9];
  float* out = (float*)d_out;

  char* ws = (char*)d_ws;
  u16*   xbuf   = (u16*)(ws);                     // 327,680,000
  u16*   hbf    = (u16*)(ws + 327680000);         // 10,240,000
  float* h1     = (float*)(ws + 337920000);       // 20,480,000
  u16*   w1t    = (u16*)(ws + 358400000);         // 393,216
  u16*   w2t    = (u16*)(ws + 358793216);         // 196,608
  float* stats  = (float*)(ws + 358989824);       // 131,072
  float* ab     = (float*)(ws + 359120896);       // 2,048
  int*   cnt    = (int*)(ws + 359122944);         // 160,000
  int*   cursor = (int*)(ws + 359282944);         // 160,000
  int*   srcS   = (int*)(ws + 359442944);         // 2,560,000
  int*   dstS   = (int*)(ws + 362002944);         // 2,560,000
  int*   rank   = (int*)(ws + 364562944);         // 2,560,000
  u16*   ebfS   = (u16*)(ws + 367122944);         // 163,840,000 -> need 530,962,944
  const bool SORTED = ws_size >= 530962944ULL;

  prep_weights<<<144, 256, 0, stream>>>(W1, W2, w1t, w2t);
  cvt_vec<<<2500, 256, 0, stream>>>(h, hbf, 640000, 0);  // h -> bf16

  if (SORTED) {
    hipMemsetAsync(cnt, 0, 160000, stream);
    hist_dst<<<2500, 256, 0, stream>>>(dst, cnt);
    scan_hist<<<1, 1024, 0, stream>>>(cnt, cursor);
    rank_edges<<<2500, 256, 0, stream>>>(src, dst, cursor, srcS, dstS, rank);
    permute_e<<<10000, 256, 0, stream>>>(e, rank, ebfS);  // sorted raw bf16 e
  }

  const int nblk = N_EDGES / 64;  // 10000
  for (int l = 0; l < 3; ++l) {
    hipMemsetAsync(stats, 0, 64 * 512 * 4, stream);
    if (SORTED)
      gin_g1<2><<<nblk, 256, 0, stream>>>(hbf, nullptr, ebfS, srcS,
                                          w1t + (size_t)l * 65536, xbuf, stats);
    else if (l == 0)
      gin_g1<0><<<nblk, 256, 0, stream>>>(hbf, e, nullptr, src, w1t, xbuf, stats);
    else
      gin_g1<1><<<nblk, 256, 0, stream>>>(hbf, e, nullptr, src,
                                          w1t + (size_t)l * 65536, xbuf, stats);
    if (SORTED && l == 0)  // e := relu(e) for layers 1,2 (in place, packed bf16)
      relu_bf16_inplace<<<80000, 256, 0, stream>>>((unsigned int*)ebfS, 20480000);
    gin_bnstats<<<1, 256, 0, stream>>>(stats, gamma + l * 256, beta + l * 256, ab);
    float* hnext = (l < 2) ? h1 : out;
    hipMemsetAsync(hnext, 0, (size_t)N_NODES * 128 * 4, stream);
    if (SORTED)
      gin_g2<true><<<nblk, 256, 0, stream>>>(xbuf, w2t + (size_t)l * 32768, ab,
                                             b2 + l * 128, dstS, hnext);
    else
      gin_g2<false><<<nblk, 256, 0, stream>>>(xbuf, w2t + (size_t)l * 32768, ab,
                                              b2 + l * 128, dst, hnext);
    if (l < 2) cvt_vec<<<2500, 256, 0, stream>>>(h1, hbf, 640000, 1);
  }
}